// Round 5
// baseline (457.463 us; speedup 1.0000x reference)
//
#include <hip/hip_runtime.h>
#include <hip/hip_bf16.h>
#include <stdint.h>

#define B_ 2
#define T_ 2048
#define C_ 2048
#define H_ 16
#define HKV_ 4
#define D_ 128
#define M_ (B_*T_)          // 4096 rows of hidden_states
// scale * log2(e): exp(x*scale) == exp2(x * SCL)
static constexpr float SCL = 0.08838834764831845f * 1.4426950408889634f;
static constexpr float EPS_ = 1e-6f;

typedef short bf16x8 __attribute__((ext_vector_type(8)));
typedef float f32x4 __attribute__((ext_vector_type(4)));

__device__ __forceinline__ f32x4 zero4() {
  f32x4 v; v[0] = 0.f; v[1] = 0.f; v[2] = 0.f; v[3] = 0.f; return v;
}

__device__ __forceinline__ unsigned short f2bf(float x) {
  union { float f; unsigned u; } v; v.f = x;
  unsigned r = (v.u + 0x7FFFu + ((v.u >> 16) & 1u)) >> 16;
  return (unsigned short)r;
}

__device__ __forceinline__ void gl_lds16(const void* g, void* l) {
  __builtin_amdgcn_global_load_lds((const __attribute__((address_space(1))) void*)g,
                                   (__attribute__((address_space(3))) void*)l, 16, 0, 0);
}

// ---------------- f32 -> bf16 elementwise convert ----------------
__global__ void k_cvt(const float* __restrict__ in, unsigned short* __restrict__ out, int n) {
  int i = (blockIdx.x * blockDim.x + threadIdx.x) * 8;
  int stride = gridDim.x * blockDim.x * 8;
  for (; i < n; i += stride) {
    float4 a = *(const float4*)(in + i);
    float4 b = *(const float4*)(in + i + 4);
    ushort4 o0; o0.x = f2bf(a.x); o0.y = f2bf(a.y); o0.z = f2bf(a.z); o0.w = f2bf(a.w);
    ushort4 o1; o1.x = f2bf(b.x); o1.y = f2bf(b.y); o1.z = f2bf(b.z); o1.w = f2bf(b.w);
    *(ushort4*)(out + i) = o0;
    *(ushort4*)(out + i + 4) = o1;
  }
}

// ------------- f32 -> bf16 transpose convert: out[c][r] = in[r][c] -------------
__global__ void k_cvt_t(const float* __restrict__ in, unsigned short* __restrict__ out,
                        int R, int Cc) {
  __shared__ float ld[32][33];
  int c0 = blockIdx.x * 32, r0 = blockIdx.y * 32;
  int x = threadIdx.x, y = threadIdx.y; // 32 x 8
#pragma unroll
  for (int i = 0; i < 4; i++)
    ld[y * 4 + i][x] = in[(size_t)(r0 + y * 4 + i) * Cc + c0 + x];
  __syncthreads();
#pragma unroll
  for (int i = 0; i < 4; i++)
    out[(size_t)(c0 + y * 4 + i) * R + r0 + x] = f2bf(ld[x][y * 4 + i]);
}

// ---------------- keep-mask -> 64-word bitmask ----------------
__global__ void k_maskbits(const int* __restrict__ mask, unsigned int* __restrict__ mb) {
  int t = threadIdx.x;
  if (t < 64) {
    unsigned int w = 0;
    for (int b = 0; b < 32; b++)
      if (mask[t * 32 + b] != 0) w |= (1u << b);
    mb[t] = w;
  }
}

// ---------------- bf16 GEMM: C[M][N] = A[M][K] * Bt[N][K]^T ----------------
// BM=BN=128, BK=64, 256 threads (4 waves, 2x2), wave tile 64x64.
// 1-D grid with XCD swizzle (T1): each XCD's contiguous sw-range shares A-row panels.
template <int WRITE_F32>
__global__ __launch_bounds__(256) void k_gemm(const unsigned short* __restrict__ A,
                                              const unsigned short* __restrict__ Bt,
                                              void* __restrict__ Cout,
                                              int Mdim, int Ndim, int K, int nbx) {
  __shared__ __align__(16) unsigned short As[128 * 64];
  __shared__ __align__(16) unsigned short Bs[128 * 64];
  const int tid = threadIdx.x;
  const int wid = tid >> 6, lane = tid & 63;
  const int wm = wid >> 1, wn = wid & 1;
  const int nq = gridDim.x >> 3;               // nwg/8 (all grids %8==0)
  const int id = blockIdx.x;
  const int sw = (id & 7) * nq + (id >> 3);    // XCD-contiguous remap
  const int m0 = (sw / nbx) * 128, n0 = (sw % nbx) * 128;
  const int lrow = tid >> 3, lcol = (tid & 7) * 8;
  const int g = lane >> 4, lr = lane & 15;

  f32x4 acc[4][4];
#pragma unroll
  for (int i = 0; i < 4; i++)
#pragma unroll
    for (int j = 0; j < 4; j++) acc[i][j] = zero4();

  for (int k0 = 0; k0 < K; k0 += 64) {
    __syncthreads();
#pragma unroll
    for (int it = 0; it < 4; it++) {
      gl_lds16(A + (size_t)(m0 + lrow + it * 32) * K + k0 + lcol, (void*)(As + tid * 8 + it * 2048));
      gl_lds16(Bt + (size_t)(n0 + lrow + it * 32) * K + k0 + lcol, (void*)(Bs + tid * 8 + it * 2048));
    }
    __syncthreads();
#pragma unroll
    for (int kk = 0; kk < 2; kk++) {
      bf16x8 af[4], bfr[4];
#pragma unroll
      for (int i = 0; i < 4; i++)
        af[i] = *(const bf16x8*)(As + (wm * 64 + i * 16 + lr) * 64 + kk * 32 + g * 8);
#pragma unroll
      for (int j = 0; j < 4; j++)
        bfr[j] = *(const bf16x8*)(Bs + (wn * 64 + j * 16 + lr) * 64 + kk * 32 + g * 8);
#pragma unroll
      for (int i = 0; i < 4; i++)
#pragma unroll
        for (int j = 0; j < 4; j++)
          acc[i][j] = __builtin_amdgcn_mfma_f32_16x16x32_bf16(af[i], bfr[j], acc[i][j], 0, 0, 0);
    }
  }

#pragma unroll
  for (int i = 0; i < 4; i++)
#pragma unroll
    for (int j = 0; j < 4; j++)
#pragma unroll
      for (int r = 0; r < 4; r++) {
        int row = m0 + wm * 64 + i * 16 + g * 4 + r;
        int col = n0 + wn * 64 + j * 16 + lr;
        if (WRITE_F32)
          ((float*)Cout)[(size_t)row * Ndim + col] = acc[i][j][r];
        else
          ((unsigned short*)Cout)[(size_t)row * Ndim + col] = f2bf(acc[i][j][r]);
      }
}

// ---------------- fused causal GQA attention with prune+renorm ----------------
// 512 threads = 8 waves; QBLK=128 (wave w owns q-rows qbase+w*16..+15), KVBLK=64.
// R2's proven sync structure (2 full barriers/tile, no dbuf). LDS 48 KB, 2 blocks/CU.
// Grid 512 blocks 1-D: id%8 = XCD = bh>>2, so each XCD streams ONE (b,hkv) K/V panel.
// T2: XOR-swizzle byte^((row&7)<<4) on K/V/Ps; gl_lds dest linear, global src pre-swizzled.
__global__ __launch_bounds__(512, 4) void k_attn(const unsigned short* __restrict__ qb,  // [4096][2048]
                                                 const unsigned short* __restrict__ kb,  // [4096][512]
                                                 const unsigned short* __restrict__ vt,  // [512][4096]
                                                 const unsigned int* __restrict__ mb,    // [64] bitmask
                                                 float* __restrict__ attn,               // [B,H,T,S]
                                                 unsigned short* __restrict__ ctx)       // [4096][2048]
{
  __shared__ __align__(16) unsigned short Ks[64 * 128];   // 16 KB
  __shared__ __align__(16) unsigned short Vs[128 * 64];   // 16 KB
  __shared__ __align__(16) unsigned short Ps[8][16 * 64]; // 16 KB

  const int tid = threadIdx.x;
  const int wid = tid >> 6, lane = tid & 63;
  const int g = lane >> 4, lr = lane & 15;
  const int lr7 = lr & 7;
  const int id = blockIdx.x;
  const int bh = (id & 7) * 4 + ((id >> 3) & 3);  // XCD = bh>>2
  const int qt = 15 - (id >> 5);                  // heavy q-tiles first (LPT)
  const int b = bh >> 4, h = bh & 15, hkv = h >> 2;
  const int qbase = qt * 128;
  const int ntile = 2 * qt + 2;                   // 64-wide s-tiles covering [0, qbase+128)

  const unsigned short* qp = qb + (size_t)(b * T_ + qbase) * 2048 + h * 128;
  const unsigned short* kp = kb + (size_t)(b * T_) * 512 + hkv * 128;
  const unsigned short* vp = vt + (size_t)(hkv * 128) * 4096 + b * T_;
  float* ap = attn + (size_t)(bh * T_ + qbase) * 2048;
  unsigned short* cp = ctx + (size_t)(b * T_ + qbase) * 2048 + h * 128;

  // Q fragments (held in registers for both passes)
  bf16x8 qa[4];
#pragma unroll
  for (int ks = 0; ks < 4; ks++)
    qa[ks] = *(const bf16x8*)(qp + (size_t)(wid * 16 + lr) * 2048 + ks * 32 + g * 8);

  // staging geometry with pre-swizzled global source columns (LDS dest stays linear)
  const int srow = tid >> 4;                                   // K: 16 thr/row (256B), rows 0..31
  const int scolb = ((tid & 15) * 16) ^ ((srow & 7) << 4);
  const int vrow = tid >> 3;                                   // V: 8 thr/row (128B), rows 0..63
  const int vcolb = ((tid & 7) * 16) ^ ((vrow & 7) << 4);

  auto stageK = [&](int st) {
    const unsigned short* src = kp + (size_t)(st * 64 + srow) * 512 + (scolb >> 1);
    unsigned short* dst = Ks + tid * 8;
#pragma unroll
    for (int it = 0; it < 2; it++)
      gl_lds16(src + (size_t)it * 32 * 512, (void*)(dst + it * 4096));
  };
  auto stageV = [&](int st) {
    const unsigned short* src = vp + (size_t)vrow * 4096 + st * 64 + (vcolb >> 1);
    unsigned short* dst = Vs + tid * 8;
#pragma unroll
    for (int it = 0; it < 2; it++)
      gl_lds16(src + (size_t)it * 64 * 4096, (void*)(dst + it * 4096));
  };

  float z[4] = {0, 0, 0, 0}, zk[4] = {0, 0, 0, 0};

  // ---- pass 1: row sums Z (all causal) and S_keep (kept causal) ----
  for (int st = 0; st < ntile; st++) {
    __syncthreads();
    stageK(st);
    __syncthreads();
#pragma unroll
    for (int j = 0; j < 4; j++) {
      f32x4 sc = zero4();
      const unsigned short* kbase = Ks + (j * 16 + lr) * 128;
#pragma unroll
      for (int ks = 0; ks < 4; ks++) {
        bf16x8 kf = *(const bf16x8*)(kbase + (((ks * 64 + g * 16) ^ (lr7 << 4)) >> 1));
        sc = __builtin_amdgcn_mfma_f32_16x16x32_bf16(qa[ks], kf, sc, 0, 0, 0);
      }
      int sg = st * 64 + j * 16 + lr;
      unsigned int w = mb[st * 2 + (j >> 1)];                  // uniform scalar load
      float kpv = (float)((w >> ((j & 1) * 16 + lr)) & 1u);
#pragma unroll
      for (int r = 0; r < 4; r++) {
        int tg = qbase + wid * 16 + g * 4 + r;
        float e = (sg <= tg) ? __builtin_amdgcn_exp2f(sc[r] * SCL) : 0.0f;
        z[r] += e;
        zk[r] += e * kpv;
      }
    }
  }
#pragma unroll
  for (int r = 0; r < 4; r++) {
#pragma unroll
    for (int m = 1; m < 16; m <<= 1) {
      z[r] += __shfl_xor(z[r], m);
      zk[r] += __shfl_xor(zk[r], m);
    }
  }
  float inv[4];
#pragma unroll
  for (int r = 0; r < 4; r++) inv[r] = 1.0f / (zk[r] + EPS_ * z[r]);

  f32x4 cacc[8];
#pragma unroll
  for (int n = 0; n < 8; n++) cacc[n] = zero4();

  // ---- pass 2 (descending: reuse L2-hot tail K): attn write + PV ----
  for (int st = ntile - 1; st >= 0; st--) {
    __syncthreads();
    stageK(st);
    stageV(st);
    __syncthreads();
    const int s0 = st * 64;
#pragma unroll
    for (int j = 0; j < 4; j++) {
      f32x4 sc = zero4();
      const unsigned short* kbase = Ks + (j * 16 + lr) * 128;
#pragma unroll
      for (int ks = 0; ks < 4; ks++) {
        bf16x8 kf = *(const bf16x8*)(kbase + (((ks * 64 + g * 16) ^ (lr7 << 4)) >> 1));
        sc = __builtin_amdgcn_mfma_f32_16x16x32_bf16(qa[ks], kf, sc, 0, 0, 0);
      }
      int sg = s0 + j * 16 + lr;
      unsigned int w = mb[st * 2 + (j >> 1)];
      float kpv = (float)((w >> ((j & 1) * 16 + lr)) & 1u);
#pragma unroll
      for (int r = 0; r < 4; r++) {
        int row = wid * 16 + g * 4 + r;
        int tg = qbase + row;
        float e = (sg <= tg) ? __builtin_amdgcn_exp2f(sc[r] * SCL) : 0.0f;
        float a = e * kpv * inv[r];
        ap[(size_t)row * 2048 + sg] = a;
        int prow = g * 4 + r;
        Ps[wid][prow * 64 + (((j * 32 + lr * 2) ^ ((prow & 7) << 4)) >> 1)] = f2bf(a);
      }
    }
    asm volatile("s_waitcnt lgkmcnt(0)" ::: "memory");
    __builtin_amdgcn_sched_barrier(0);
#pragma unroll
    for (int kk = 0; kk < 2; kk++) {
      bf16x8 pa = *(const bf16x8*)(&Ps[wid][lr * 64 + (((kk * 64 + g * 16) ^ (lr7 << 4)) >> 1)]);
#pragma unroll
      for (int n = 0; n < 8; n++) {
        int vrw = n * 16 + lr;
        bf16x8 vf = *(const bf16x8*)(Vs + vrw * 64 + (((kk * 64 + g * 16) ^ ((vrw & 7) << 4)) >> 1));
        cacc[n] = __builtin_amdgcn_mfma_f32_16x16x32_bf16(pa, vf, cacc[n], 0, 0, 0);
      }
    }
  }

  // ---- epilogue: ctx write + zero-fill of the strict upper triangle ----
#pragma unroll
  for (int n = 0; n < 8; n++)
#pragma unroll
    for (int r = 0; r < 4; r++)
      cp[(size_t)(wid * 16 + g * 4 + r) * 2048 + n * 16 + lr] = f2bf(cacc[n][r]);

  const int zc0 = qbase + 128;
  if (zc0 < 2048) {
    float4 zf; zf.x = 0.f; zf.y = 0.f; zf.z = 0.f; zf.w = 0.f;
    float* aprow = ap + (size_t)(tid >> 2) * 2048;
    for (int c = zc0 + (tid & 3) * 4; c < 2048; c += 16)
      *(float4*)(aprow + c) = zf;
  }
}

extern "C" void kernel_launch(void* const* d_in, const int* in_sizes, int n_in,
                              void* d_out, int out_size, void* d_ws, size_t ws_size,
                              hipStream_t stream) {
  const float* hs = (const float*)d_in[0];
  const float* Wq = (const float*)d_in[1];
  const float* Wk = (const float*)d_in[2];
  const float* Wv = (const float*)d_in[3];
  const float* Wo = (const float*)d_in[4];
  const int* mask = (const int*)d_in[5];

  char* w = (char*)d_ws;
  unsigned short* hsb = (unsigned short*)w; w += (size_t)M_ * C_ * 2;        // 16 MB
  unsigned short* Wqt = (unsigned short*)w; w += (size_t)2048 * 2048 * 2;    // 8 MB
  unsigned short* Wkt = (unsigned short*)w; w += (size_t)512 * 2048 * 2;     // 2 MB
  unsigned short* Wvt = (unsigned short*)w; w += (size_t)512 * 2048 * 2;     // 2 MB
  unsigned short* Wot = (unsigned short*)w; w += (size_t)2048 * 2048 * 2;    // 8 MB
  unsigned short* qbuf = (unsigned short*)w; w += (size_t)M_ * 2048 * 2;     // 16 MB
  unsigned short* kbuf = (unsigned short*)w; w += (size_t)M_ * 512 * 2;      // 4 MB
  unsigned short* vtb = (unsigned short*)w; w += (size_t)512 * M_ * 2;       // 4 MB
  unsigned short* ctxb = (unsigned short*)w; w += (size_t)M_ * 2048 * 2;     // 16 MB
  unsigned int* mbits = (unsigned int*)w;  w += 256;                          // 64 words

  float* out = (float*)d_out;
  float* attn = out + (size_t)M_ * C_;

  // convert / transpose weights + activations to bf16; build keep bitmask
  k_cvt<<<2048, 256, 0, stream>>>(hs, hsb, M_ * C_);
  k_cvt_t<<<dim3(2048 / 32, 2048 / 32), dim3(32, 8), 0, stream>>>(Wq, Wqt, 2048, 2048);
  k_cvt_t<<<dim3(512 / 32, 2048 / 32), dim3(32, 8), 0, stream>>>(Wk, Wkt, 2048, 512);
  k_cvt_t<<<dim3(512 / 32, 2048 / 32), dim3(32, 8), 0, stream>>>(Wv, Wvt, 2048, 512);
  k_cvt_t<<<dim3(2048 / 32, 2048 / 32), dim3(32, 8), 0, stream>>>(Wo, Wot, 2048, 2048);
  k_maskbits<<<1, 64, 0, stream>>>(mask, mbits);

  // projections: q [4096,2048], k [4096,512], v^T [512,4096] (via swapped operands)
  k_gemm<0><<<512, 256, 0, stream>>>(hsb, Wqt, qbuf, 4096, 2048, 2048, 16);
  k_gemm<0><<<128, 256, 0, stream>>>(hsb, Wkt, kbuf, 4096, 512, 2048, 4);
  k_gemm<0><<<128, 256, 0, stream>>>(Wvt, hsb, vtb, 512, 4096, 2048, 32);

  // fused attention: attn_w (f32, pruned+renormalized) + ctx (bf16)
  k_attn<<<512, 512, 0, stream>>>(qbuf, kbuf, vtb, mbits, attn, ctxb);

  // output projection (f32 out)
  k_gemm<1><<<512, 256, 0, stream>>>(ctxb, Wot, out, 4096, 2048, 2048, 16);
}

// Round 6
// 456.729 us; speedup vs baseline: 1.0016x; 1.0016x over previous
//
#include <hip/hip_runtime.h>
#include <hip/hip_bf16.h>
#include <stdint.h>

#define B_ 2
#define T_ 2048
#define C_ 2048
#define H_ 16
#define HKV_ 4
#define D_ 128
#define M_ (B_*T_)          // 4096 rows of hidden_states
// scale * log2(e): exp(x*scale) == exp2(x * SCL)
static constexpr float SCL = 0.08838834764831845f * 1.4426950408889634f;
static constexpr float EPS_ = 1e-6f;

typedef short bf16x8 __attribute__((ext_vector_type(8)));
typedef float f32x4 __attribute__((ext_vector_type(4)));

__device__ __forceinline__ f32x4 zero4() {
  f32x4 v; v[0] = 0.f; v[1] = 0.f; v[2] = 0.f; v[3] = 0.f; return v;
}

// native bf16 convert (m240: scalar casts fuse to v_cvt_pk_bf16_f32)
__device__ __forceinline__ unsigned short f2bf(float x) {
  union { __bf16 h; unsigned short u; } v;
  v.h = (__bf16)x;
  return v.u;
}

__device__ __forceinline__ void gl_lds16(const void* g, void* l) {
  __builtin_amdgcn_global_load_lds((const __attribute__((address_space(1))) void*)g,
                                   (__attribute__((address_space(3))) void*)l, 16, 0, 0);
}

// ---------------- f32 -> bf16 elementwise convert ----------------
__global__ void k_cvt(const float* __restrict__ in, unsigned short* __restrict__ out, int n) {
  int i = (blockIdx.x * blockDim.x + threadIdx.x) * 8;
  int stride = gridDim.x * blockDim.x * 8;
  for (; i < n; i += stride) {
    float4 a = *(const float4*)(in + i);
    float4 b = *(const float4*)(in + i + 4);
    ushort4 o0; o0.x = f2bf(a.x); o0.y = f2bf(a.y); o0.z = f2bf(a.z); o0.w = f2bf(a.w);
    ushort4 o1; o1.x = f2bf(b.x); o1.y = f2bf(b.y); o1.z = f2bf(b.z); o1.w = f2bf(b.w);
    *(ushort4*)(out + i) = o0;
    *(ushort4*)(out + i + 4) = o1;
  }
}

// ------------- f32 -> bf16 transpose convert: out[c][r] = in[r][c] -------------
__global__ void k_cvt_t(const float* __restrict__ in, unsigned short* __restrict__ out,
                        int R, int Cc) {
  __shared__ float ld[32][33];
  int c0 = blockIdx.x * 32, r0 = blockIdx.y * 32;
  int x = threadIdx.x, y = threadIdx.y; // 32 x 8
#pragma unroll
  for (int i = 0; i < 4; i++)
    ld[y * 4 + i][x] = in[(size_t)(r0 + y * 4 + i) * Cc + c0 + x];
  __syncthreads();
#pragma unroll
  for (int i = 0; i < 4; i++)
    out[(size_t)(c0 + y * 4 + i) * R + r0 + x] = f2bf(ld[x][y * 4 + i]);
}

// ---------------- keep-mask -> 64-word bitmask ----------------
__global__ void k_maskbits(const int* __restrict__ mask, unsigned int* __restrict__ mb) {
  int t = threadIdx.x;
  if (t < 64) {
    unsigned int w = 0;
    for (int b = 0; b < 32; b++)
      if (mask[t * 32 + b] != 0) w |= (1u << b);
    mb[t] = w;
  }
}

// ---------------- bf16 GEMM: C[M][N] = A[M][K] * Bt[N][K]^T ----------------
// BM=BN=128, BK=64, 256 threads (4 waves, 2x2), wave tile 64x64 (R2-proven structure)
template <int WRITE_F32>
__global__ __launch_bounds__(256) void k_gemm(const unsigned short* __restrict__ A,
                                              const unsigned short* __restrict__ Bt,
                                              void* __restrict__ Cout,
                                              int Mdim, int Ndim, int K) {
  __shared__ __align__(16) unsigned short As[128 * 64];
  __shared__ __align__(16) unsigned short Bs[128 * 64];
  const int tid = threadIdx.x;
  const int wid = tid >> 6, lane = tid & 63;
  const int wm = wid >> 1, wn = wid & 1;
  const int m0 = blockIdx.y * 128, n0 = blockIdx.x * 128;
  const int lrow = tid >> 3, lcol = (tid & 7) * 8;
  const int g = lane >> 4, lr = lane & 15;

  f32x4 acc[4][4];
#pragma unroll
  for (int i = 0; i < 4; i++)
#pragma unroll
    for (int j = 0; j < 4; j++) acc[i][j] = zero4();

  for (int k0 = 0; k0 < K; k0 += 64) {
    __syncthreads();
#pragma unroll
    for (int it = 0; it < 4; it++) {
      gl_lds16(A + (size_t)(m0 + lrow + it * 32) * K + k0 + lcol, (void*)(As + tid * 8 + it * 2048));
      gl_lds16(Bt + (size_t)(n0 + lrow + it * 32) * K + k0 + lcol, (void*)(Bs + tid * 8 + it * 2048));
    }
    __syncthreads();
#pragma unroll
    for (int kk = 0; kk < 2; kk++) {
      bf16x8 af[4], bfr[4];
#pragma unroll
      for (int i = 0; i < 4; i++)
        af[i] = *(const bf16x8*)(As + (wm * 64 + i * 16 + lr) * 64 + kk * 32 + g * 8);
#pragma unroll
      for (int j = 0; j < 4; j++)
        bfr[j] = *(const bf16x8*)(Bs + (wn * 64 + j * 16 + lr) * 64 + kk * 32 + g * 8);
#pragma unroll
      for (int i = 0; i < 4; i++)
#pragma unroll
        for (int j = 0; j < 4; j++)
          acc[i][j] = __builtin_amdgcn_mfma_f32_16x16x32_bf16(af[i], bfr[j], acc[i][j], 0, 0, 0);
    }
  }

#pragma unroll
  for (int i = 0; i < 4; i++)
#pragma unroll
    for (int j = 0; j < 4; j++)
#pragma unroll
      for (int r = 0; r < 4; r++) {
        int row = m0 + wm * 64 + i * 16 + g * 4 + r;
        int col = n0 + wn * 64 + j * 16 + lr;
        if (WRITE_F32)
          ((float*)Cout)[(size_t)row * Ndim + col] = acc[i][j][r];
        else
          ((unsigned short*)Cout)[(size_t)row * Ndim + col] = f2bf(acc[i][j][r]);
      }
}

// ---------------- fused causal GQA attention with prune+renorm ----------------
// grid (32 b*h, 32 qtiles[reversed LPT]), 256 threads = 4 waves. R2 sync structure.
// LDS 40 KB -> 4 blocks/CU (16 waves/CU). Pass 1 stages 128-row K tiles (Ks+Vs aliased).
// T2: XOR-swizzle byte^((row&7)<<4); gl_lds dest linear, global src pre-swizzled.
__global__ __launch_bounds__(256, 4) void k_attn(const unsigned short* __restrict__ qb,  // [4096][2048]
                                                 const unsigned short* __restrict__ kb,  // [4096][512]
                                                 const unsigned short* __restrict__ vt,  // [512][4096]
                                                 const unsigned int* __restrict__ mb,    // [64] bitmask
                                                 float* __restrict__ attn,               // [B,H,T,S]
                                                 unsigned short* __restrict__ ctx)       // [4096][2048]
{
  __shared__ __align__(16) unsigned short KV[128 * 128];  // 32 KB; pass2: Ks=KV, Vs=KV+8192
  __shared__ __align__(16) unsigned short Ps[4][16 * 64]; // 8 KB
  unsigned short* Ks = KV;
  unsigned short* Vs = KV + 64 * 128;

  const int tid = threadIdx.x;
  const int wid = tid >> 6, lane = tid & 63;
  const int g = lane >> 4, lr = lane & 15;
  const int lr7 = lr & 7;
  const int qt = 31 - blockIdx.y;     // heavy q-tiles dispatched first (LPT)
  const int bh = blockIdx.x;
  const int b = bh >> 4, h = bh & 15, hkv = h >> 2;
  const int qbase = qt * 64;

  const unsigned short* qp = qb + (size_t)(b * T_ + qbase) * 2048 + h * 128;
  const unsigned short* kp = kb + (size_t)(b * T_) * 512 + hkv * 128;
  const unsigned short* vp = vt + (size_t)(hkv * 128) * 4096 + b * T_;
  float* ap = attn + (size_t)(bh * T_ + qbase) * 2048;
  unsigned short* cp = ctx + (size_t)(b * T_ + qbase) * 2048 + h * 128;

  // Q fragments (held in registers for both passes)
  bf16x8 qa[4];
#pragma unroll
  for (int ks = 0; ks < 4; ks++)
    qa[ks] = *(const bf16x8*)(qp + (size_t)(wid * 16 + lr) * 2048 + ks * 32 + g * 8);

  // staging geometry with pre-swizzled global source columns (LDS dest stays linear)
  const int srow = tid >> 4;                                   // K: 16 thr/row (256B)
  const int scolb = ((tid & 15) * 16) ^ ((srow & 7) << 4);
  const int vrow = tid >> 3;                                   // V: 8 thr/row (128B)
  const int vcolb = ((tid & 7) * 16) ^ ((vrow & 7) << 4);

  float z[4] = {0, 0, 0, 0}, zk[4] = {0, 0, 0, 0};

  // ---- pass 1: 128-row K tiles; row sums Z (causal) and S_keep (kept causal) ----
  const int ntile1 = (qt >> 1) + 1;
  for (int st = 0; st < ntile1; st++) {
    __syncthreads();
    {
      const unsigned short* src = kp + (size_t)(st * 128 + srow) * 512 + (scolb >> 1);
      unsigned short* dst = KV + tid * 8;
#pragma unroll
      for (int it = 0; it < 8; it++)
        gl_lds16(src + (size_t)it * 16 * 512, (void*)(dst + it * 2048));
    }
    __syncthreads();
    // per-wave uniform split: j < jcut fully causal (no compare); jcut<=j<jend masked; rest skipped
    const int dj = qbase + wid * 16 - st * 128;
    int jcut = (dj + 1) >> 4; jcut = jcut < 0 ? 0 : (jcut > 8 ? 8 : jcut);
    int jend = ((dj + 15) >> 4) + 1; jend = jend < jcut ? jcut : (jend > 8 ? 8 : jend);
    for (int j = 0; j < jcut; j++) {
      f32x4 sc = zero4();
      const unsigned short* kbase = KV + (j * 16 + lr) * 128;
#pragma unroll
      for (int ks = 0; ks < 4; ks++) {
        bf16x8 kf = *(const bf16x8*)(kbase + (((ks * 64 + g * 16) ^ (lr7 << 4)) >> 1));
        sc = __builtin_amdgcn_mfma_f32_16x16x32_bf16(qa[ks], kf, sc, 0, 0, 0);
      }
      unsigned int w = mb[st * 4 + (j >> 1)];
      float kpv = (float)((w >> ((j & 1) * 16 + lr)) & 1u);
#pragma unroll
      for (int r = 0; r < 4; r++) {
        float e = __builtin_amdgcn_exp2f(sc[r] * SCL);
        z[r] += e;
        zk[r] += e * kpv;
      }
    }
    for (int j = jcut; j < jend; j++) {
      f32x4 sc = zero4();
      const unsigned short* kbase = KV + (j * 16 + lr) * 128;
#pragma unroll
      for (int ks = 0; ks < 4; ks++) {
        bf16x8 kf = *(const bf16x8*)(kbase + (((ks * 64 + g * 16) ^ (lr7 << 4)) >> 1));
        sc = __builtin_amdgcn_mfma_f32_16x16x32_bf16(qa[ks], kf, sc, 0, 0, 0);
      }
      int sg = st * 128 + j * 16 + lr;
      unsigned int w = mb[st * 4 + (j >> 1)];
      float kpv = (float)((w >> ((j & 1) * 16 + lr)) & 1u);
#pragma unroll
      for (int r = 0; r < 4; r++) {
        int tg = qbase + wid * 16 + g * 4 + r;
        float e = (sg <= tg) ? __builtin_amdgcn_exp2f(sc[r] * SCL) : 0.0f;
        z[r] += e;
        zk[r] += e * kpv;
      }
    }
  }
#pragma unroll
  for (int r = 0; r < 4; r++) {
#pragma unroll
    for (int m = 1; m < 16; m <<= 1) {
      z[r] += __shfl_xor(z[r], m);
      zk[r] += __shfl_xor(zk[r], m);
    }
  }
  float inv[4];
#pragma unroll
  for (int r = 0; r < 4; r++) inv[r] = 1.0f / (zk[r] + EPS_ * z[r]);

  f32x4 cacc[8];
#pragma unroll
  for (int n = 0; n < 8; n++) cacc[n] = zero4();

  // ---- pass 2 (descending: diagonal tile first, then fully-causal): attn write + PV ----
  for (int st = qt; st >= 0; st--) {
    __syncthreads();
    {
      const unsigned short* srcK = kp + (size_t)(st * 64 + srow) * 512 + (scolb >> 1);
      const unsigned short* srcV = vp + (size_t)vrow * 4096 + st * 64 + (vcolb >> 1);
      unsigned short* dstK = Ks + tid * 8;
      unsigned short* dstV = Vs + tid * 8;
#pragma unroll
      for (int it = 0; it < 4; it++) {
        gl_lds16(srcK + (size_t)it * 16 * 512, (void*)(dstK + it * 2048));
        gl_lds16(srcV + (size_t)it * 32 * 4096, (void*)(dstV + it * 2048));
      }
    }
    __syncthreads();
    const int s0 = st * 64;
    const bool diag = (st == qt);
#pragma unroll
    for (int j = 0; j < 4; j++) {
      f32x4 sc = zero4();
      const unsigned short* kbase = Ks + (j * 16 + lr) * 128;
#pragma unroll
      for (int ks = 0; ks < 4; ks++) {
        bf16x8 kf = *(const bf16x8*)(kbase + (((ks * 64 + g * 16) ^ (lr7 << 4)) >> 1));
        sc = __builtin_amdgcn_mfma_f32_16x16x32_bf16(qa[ks], kf, sc, 0, 0, 0);
      }
      int sg = s0 + j * 16 + lr;
      unsigned int w = mb[st * 2 + (j >> 1)];
      float kpv = (float)((w >> ((j & 1) * 16 + lr)) & 1u);
      if (diag) {
#pragma unroll
        for (int r = 0; r < 4; r++) {
          int row = wid * 16 + g * 4 + r;
          int tg = qbase + row;
          float e = (sg <= tg) ? __builtin_amdgcn_exp2f(sc[r] * SCL) : 0.0f;
          float a = e * kpv * inv[r];
          ap[(size_t)row * 2048 + sg] = a;
          int prow = g * 4 + r;
          Ps[wid][prow * 64 + (((j * 32 + lr * 2) ^ ((prow & 7) << 4)) >> 1)] = f2bf(a);
        }
      } else {
#pragma unroll
        for (int r = 0; r < 4; r++) {
          int row = wid * 16 + g * 4 + r;
          float e = __builtin_amdgcn_exp2f(sc[r] * SCL);
          float a = e * kpv * inv[r];
          ap[(size_t)row * 2048 + sg] = a;
          int prow = g * 4 + r;
          Ps[wid][prow * 64 + (((j * 32 + lr * 2) ^ ((prow & 7) << 4)) >> 1)] = f2bf(a);
        }
      }
    }
    asm volatile("s_waitcnt lgkmcnt(0)" ::: "memory");
    __builtin_amdgcn_sched_barrier(0);
#pragma unroll
    for (int kk = 0; kk < 2; kk++) {
      bf16x8 pa = *(const bf16x8*)(&Ps[wid][lr * 64 + (((kk * 64 + g * 16) ^ (lr7 << 4)) >> 1)]);
#pragma unroll
      for (int n = 0; n < 8; n++) {
        int vrw = n * 16 + lr;
        bf16x8 vf = *(const bf16x8*)(Vs + vrw * 64 + (((kk * 64 + g * 16) ^ ((vrw & 7) << 4)) >> 1));
        cacc[n] = __builtin_amdgcn_mfma_f32_16x16x32_bf16(pa, vf, cacc[n], 0, 0, 0);
      }
    }
  }

  // ---- epilogue: ctx write + zero-fill of the strict upper triangle ----
#pragma unroll
  for (int n = 0; n < 8; n++)
#pragma unroll
    for (int r = 0; r < 4; r++)
      cp[(size_t)(wid * 16 + g * 4 + r) * 2048 + n * 16 + lr] = f2bf(cacc[n][r]);

  const int zc0 = qbase + 64;
  if (zc0 < 2048) {
    float4 zf; zf.x = 0.f; zf.y = 0.f; zf.z = 0.f; zf.w = 0.f;
    float* aprow = ap + (size_t)(tid >> 2) * 2048;
    for (int c = zc0 + (tid & 3) * 4; c < 2048; c += 16)
      *(float4*)(aprow + c) = zf;
  }
}

extern "C" void kernel_launch(void* const* d_in, const int* in_sizes, int n_in,
                              void* d_out, int out_size, void* d_ws, size_t ws_size,
                              hipStream_t stream) {
  const float* hs = (const float*)d_in[0];
  const float* Wq = (const float*)d_in[1];
  const float* Wk = (const float*)d_in[2];
  const float* Wv = (const float*)d_in[3];
  const float* Wo = (const float*)d_in[4];
  const int* mask = (const int*)d_in[5];

  char* w = (char*)d_ws;
  unsigned short* hsb = (unsigned short*)w; w += (size_t)M_ * C_ * 2;        // 16 MB
  unsigned short* Wqt = (unsigned short*)w; w += (size_t)2048 * 2048 * 2;    // 8 MB
  unsigned short* Wkt = (unsigned short*)w; w += (size_t)512 * 2048 * 2;     // 2 MB
  unsigned short* Wvt = (unsigned short*)w; w += (size_t)512 * 2048 * 2;     // 2 MB
  unsigned short* Wot = (unsigned short*)w; w += (size_t)2048 * 2048 * 2;    // 8 MB
  unsigned short* qbuf = (unsigned short*)w; w += (size_t)M_ * 2048 * 2;     // 16 MB
  unsigned short* kbuf = (unsigned short*)w; w += (size_t)M_ * 512 * 2;      // 4 MB
  unsigned short* vtb = (unsigned short*)w; w += (size_t)512 * M_ * 2;       // 4 MB
  unsigned short* ctxb = (unsigned short*)w; w += (size_t)M_ * 2048 * 2;     // 16 MB
  unsigned int* mbits = (unsigned int*)w;  w += 256;                          // 64 words

  float* out = (float*)d_out;
  float* attn = out + (size_t)M_ * C_;

  // convert / transpose weights + activations to bf16; build keep bitmask
  k_cvt<<<2048, 256, 0, stream>>>(hs, hsb, M_ * C_);
  k_cvt_t<<<dim3(2048 / 32, 2048 / 32), dim3(32, 8), 0, stream>>>(Wq, Wqt, 2048, 2048);
  k_cvt_t<<<dim3(512 / 32, 2048 / 32), dim3(32, 8), 0, stream>>>(Wk, Wkt, 2048, 512);
  k_cvt_t<<<dim3(512 / 32, 2048 / 32), dim3(32, 8), 0, stream>>>(Wv, Wvt, 2048, 512);
  k_cvt_t<<<dim3(2048 / 32, 2048 / 32), dim3(32, 8), 0, stream>>>(Wo, Wot, 2048, 2048);
  k_maskbits<<<1, 64, 0, stream>>>(mask, mbits);

  // projections: q [4096,2048], k [4096,512], v^T [512,4096] (via swapped operands)
  k_gemm<0><<<dim3(2048 / 128, 4096 / 128), 256, 0, stream>>>(hsb, Wqt, qbuf, 4096, 2048, 2048);
  k_gemm<0><<<dim3(512 / 128, 4096 / 128), 256, 0, stream>>>(hsb, Wkt, kbuf, 4096, 512, 2048);
  k_gemm<0><<<dim3(4096 / 128, 512 / 128), 256, 0, stream>>>(Wvt, hsb, vtb, 512, 4096, 2048);

  // fused attention: attn_w (f32, pruned+renormalized) + ctx (bf16)
  k_attn<<<dim3(32, 32), 256, 0, stream>>>(qbuf, kbuf, vtb, mbits, attn, ctxb);

  // output projection (f32 out)
  k_gemm<1><<<dim3(2048 / 128, 4096 / 128), 256, 0, stream>>>(ctxb, Wot, out, 4096, 2048, 2048);
}